// Round 7
// baseline (751.147 us; speedup 1.0000x reference)
//
#include <hip/hip_runtime.h>
#include <hip/hip_bf16.h>
#include <math.h>

typedef unsigned short u16;
typedef __attribute__((ext_vector_type(8))) short bf16x8;
typedef __attribute__((ext_vector_type(4))) float f32x4;
typedef __attribute__((ext_vector_type(4))) unsigned u32x4;
typedef __attribute__((ext_vector_type(2))) unsigned u32x2;

#define N_NODES 100000
#define IN_CH 128
#define HID 256
#define EMB 128
#define N_PAIRS 500000
#define BN_EPS 1e-5f

#define TA 32   // nodes per block (kernel A)
#define PBM 64  // pairs per block (kernel B)

// ---- bf16 helpers ----
__device__ __forceinline__ u16 f2bf(float f) {            // scalar RNE (prep kernel)
    unsigned u = __builtin_bit_cast(unsigned, f);
    unsigned r = u + 0x7FFFu + ((u >> 16) & 1u);
    return (u16)(r >> 16);
}
__device__ __forceinline__ float bf2f(u16 h) {
    unsigned u = ((unsigned)h) << 16;
    return __builtin_bit_cast(float, u);
}
// packed pair conversion: low16 = bf16(a), high16 = bf16(b); compiler emits v_cvt_pk_bf16_f32
__device__ __forceinline__ unsigned pk2(float a, float b) {
    __hip_bfloat162 h = __float22bfloat162_rn(make_float2(a, b));
    unsigned u;
    __builtin_memcpy(&u, &h, sizeof(u));
    return u;
}
__device__ __forceinline__ float lo16f(unsigned u) { return __builtin_bit_cast(float, u << 16); }
__device__ __forceinline__ float hi16f(unsigned u) { return __builtin_bit_cast(float, u & 0xffff0000u); }

// ---------------------------------------------------------------------------
// Weight prep into MFMA A-operand fragment-linear layout (weights on M-side):
// idx = ((mt*KS + ks)*64 + l)*8 + j ; value = W[k][n], n = mt*16 + (l&15),
// k = ks*32 + (l>>4)*8 + j.
// ---------------------------------------------------------------------------
__global__ __launch_bounds__(256) void prep_weights(
    const float* __restrict__ SW1, const float* __restrict__ SW2,
    u16* __restrict__ w1h, u16* __restrict__ w1l,
    u16* __restrict__ w2h, u16* __restrict__ w2l)
{
    const int tid = blockIdx.x * 256 + threadIdx.x;
    if (tid < 131072) {                       // W1^T frags: 16 mt x 16 ks
        const int j = tid & 7, l = (tid >> 3) & 63, ks = (tid >> 9) & 15, mt = tid >> 13;
        const int n = mt * 16 + (l & 15);
        const int k = ks * 32 + ((l >> 4) << 3) + j;
        const float v = SW1[(size_t)k * HID + n];
        const u16 h = f2bf(v);
        w1h[tid] = h;
        w1l[tid] = f2bf(v - bf2f(h));
    } else if (tid < 131072 + 32768) {        // W2^T frags: 8 mt x 8 ks
        const int t2 = tid - 131072;
        const int j = t2 & 7, l = (t2 >> 3) & 63, ks = (t2 >> 9) & 7, mt = t2 >> 12;
        const int n = mt * 16 + (l & 15);
        const int k = ks * 32 + ((l >> 4) << 3) + j;
        const float v = SW2[(size_t)k * (HID / 2) + n];
        const u16 h = f2bf(v);
        w2h[t2] = h;
        w2l[t2] = f2bf(v - bf2f(h));
    }
}

// ---------------------------------------------------------------------------
// Kernel A: z = relu( relu(BN(clip((x-mean)/std) @ W1 + b1)) @ W2 + b2 )
// (unchanged — fp32 register-tiled)
// ---------------------------------------------------------------------------
__global__ __launch_bounds__(256) void node_mlp_kernel(
    const float* __restrict__ x,
    const float* __restrict__ x_mean,
    const float* __restrict__ x_std,
    const float* __restrict__ W1,
    const float* __restrict__ b1,
    const float* __restrict__ bn_gamma,
    const float* __restrict__ bn_beta,
    const float* __restrict__ bn_mean,
    const float* __restrict__ bn_var,
    const float* __restrict__ W2,
    const float* __restrict__ b2,
    float* __restrict__ z)
{
    __shared__ __align__(16) float xfT[IN_CH][36];
    __shared__ __align__(16) float hT[HID][36];

    const int t  = threadIdx.x;
    const int n0 = blockIdx.x * TA;

    for (int f = t; f < TA * (IN_CH / 4); f += 256) {
        const int n  = f >> 5;
        const int cg = f & 31;
        float4 v = *reinterpret_cast<const float4*>(x + (size_t)(n0 + n) * IN_CH + cg * 4);
        float vv[4] = {v.x, v.y, v.z, v.w};
        #pragma unroll
        for (int e = 0; e < 4; ++e) {
            const int c = cg * 4 + e;
            float val = vv[e];
            if (!isfinite(val)) val = 0.0f;
            val = (val - x_mean[c]) / x_std[c];
            val = fminf(fmaxf(val, -10.0f), 10.0f);
            xfT[c][n] = val;
        }
    }
    __syncthreads();

    const int i0 = t >> 6;
    const int j  = t & 63;

    {
        float acc[8][4];
        #pragma unroll
        for (int r = 0; r < 8; ++r)
            #pragma unroll
            for (int c = 0; c < 4; ++c) acc[r][c] = 0.0f;

        #pragma unroll 4
        for (int k = 0; k < IN_CH; ++k) {
            float a[8];
            *reinterpret_cast<float4*>(&a[0]) = *reinterpret_cast<const float4*>(&xfT[k][i0 * 8]);
            *reinterpret_cast<float4*>(&a[4]) = *reinterpret_cast<const float4*>(&xfT[k][i0 * 8 + 4]);
            float w[4];
            *reinterpret_cast<float4*>(w) = *reinterpret_cast<const float4*>(W1 + (size_t)k * HID + j * 4);
            #pragma unroll
            for (int r = 0; r < 8; ++r)
                #pragma unroll
                for (int c = 0; c < 4; ++c)
                    acc[r][c] = fmaf(a[r], w[c], acc[r][c]);
        }

        float b1v[4], gv[4], bev[4], mv[4], vv[4];
        *reinterpret_cast<float4*>(b1v) = *reinterpret_cast<const float4*>(b1 + j * 4);
        *reinterpret_cast<float4*>(gv)  = *reinterpret_cast<const float4*>(bn_gamma + j * 4);
        *reinterpret_cast<float4*>(bev) = *reinterpret_cast<const float4*>(bn_beta + j * 4);
        *reinterpret_cast<float4*>(mv)  = *reinterpret_cast<const float4*>(bn_mean + j * 4);
        *reinterpret_cast<float4*>(vv)  = *reinterpret_cast<const float4*>(bn_var + j * 4);

        #pragma unroll
        for (int c = 0; c < 4; ++c) {
            const float scale = gv[c] * rsqrtf(vv[c] + BN_EPS);
            float tmp[8];
            #pragma unroll
            for (int r = 0; r < 8; ++r) {
                const float hv = (acc[r][c] + b1v[c] - mv[c]) * scale + bev[c];
                tmp[r] = fmaxf(hv, 0.0f);
            }
            *reinterpret_cast<float4*>(&hT[j * 4 + c][i0 * 8])     = *reinterpret_cast<float4*>(&tmp[0]);
            *reinterpret_cast<float4*>(&hT[j * 4 + c][i0 * 8 + 4]) = *reinterpret_cast<float4*>(&tmp[4]);
        }
    }
    __syncthreads();

    {
        float acc[8][2];
        #pragma unroll
        for (int r = 0; r < 8; ++r) { acc[r][0] = 0.0f; acc[r][1] = 0.0f; }

        #pragma unroll 4
        for (int k = 0; k < HID; ++k) {
            float a[8];
            *reinterpret_cast<float4*>(&a[0]) = *reinterpret_cast<const float4*>(&hT[k][i0 * 8]);
            *reinterpret_cast<float4*>(&a[4]) = *reinterpret_cast<const float4*>(&hT[k][i0 * 8 + 4]);
            const float2 w = *reinterpret_cast<const float2*>(W2 + (size_t)k * EMB + j * 2);
            #pragma unroll
            for (int r = 0; r < 8; ++r) {
                acc[r][0] = fmaf(a[r], w.x, acc[r][0]);
                acc[r][1] = fmaf(a[r], w.y, acc[r][1]);
            }
        }
        const float2 b2v = *reinterpret_cast<const float2*>(b2 + j * 2);
        #pragma unroll
        for (int r = 0; r < 8; ++r) {
            float2 o;
            o.x = fmaxf(acc[r][0] + b2v.x, 0.0f);
            o.y = fmaxf(acc[r][1] + b2v.y, 0.0f);
            *reinterpret_cast<float2*>(z + (size_t)(n0 + i0 * 8 + r) * EMB + j * 2) = o;
        }
    }
}

// ---------------------------------------------------------------------------
// Kernel B (MFMA): 64 pairs per block, 8 waves (512 thr), 2 blocks/CU
// (__launch_bounds__(512,2): CUDA-style min-blocks semantics -> 128 VGPR cap;
//  (512,4) forced a 64-VGPR cap and massive scratch spill in round 6).
// Two-pass K for layer 1 (pass A: [s|d], pass B: [s*d | |s-d|] rebuilt from
// quantized s,d). Weights (A-operand) stream from L2 with register dbuf.
// Feature frag layout (B-operand): addr = (ks*4 + nt)*512 + (r + 16*q)*8 + j
//   <-> feat[pair = nt*16 + r][k = ks*32 + q*8 + j]
// ---------------------------------------------------------------------------
__global__ __launch_bounds__(512, 2) void pair_mfma_kernel(
    const float* __restrict__ z,
    const int* __restrict__ pairs,
    const float* __restrict__ logdeg,
    const u16* __restrict__ w1h, const u16* __restrict__ w1l,
    const u16* __restrict__ w2h, const u16* __restrict__ w2l,
    const float* __restrict__ SW1, const float* __restrict__ Sb1,
    const float* __restrict__ Sb2,
    const float* __restrict__ SW3, const float* __restrict__ Sb3,
    float* __restrict__ out)
{
    __shared__ __align__(16) u16 F[2 * 16384];   // 64 KB: [half][slot 0..7][nt 0..3][512]
    __shared__ float red[8][4][16];

    const int t   = threadIdx.x;
    const int w   = t >> 6;        // wave 0..7
    const int l   = t & 63;
    const int l15 = l & 15;
    const int l4  = l >> 4;
    const int p0  = blockIdx.x * PBM;

    // split 8 floats (vals[off..off+8)) and store hi/lo u32x4 at u16-index base
    #define SPLIT_STORE8(vals, off, base) { \
        u32x4 hv, lv; \
        _Pragma("unroll") \
        for (int q = 0; q < 4; ++q) { \
            const float a = (vals)[(off) + 2 * q]; \
            const float b = (vals)[(off) + 2 * q + 1]; \
            const unsigned hw = pk2(a, b); \
            hv[q] = hw; \
            lv[q] = pk2(a - lo16f(hw), b - hi16f(hw)); \
        } \
        *reinterpret_cast<u32x4*>(&F[(base)])         = hv; \
        *reinterpret_cast<u32x4*>(&F[16384 + (base)]) = lv; }

    // ---- phase 0: gather s,d (pair = l, channels [w*16, w*16+16)) ----
    {
        const int gp  = (p0 + l < N_PAIRS) ? (p0 + l) : (N_PAIRS - 1);
        const int gsi = pairs[(size_t)gp * 2 + 0];
        const int gdi = pairs[(size_t)gp * 2 + 1];
        const float* zs = z + (size_t)gsi * EMB + w * 16;
        const float* zd = z + (size_t)gdi * EMB + w * 16;
        float sv[16], dv[16];
        #pragma unroll
        for (int q = 0; q < 4; ++q) {
            *reinterpret_cast<float4*>(&sv[q * 4]) = *reinterpret_cast<const float4*>(zs + q * 4);
            *reinterpret_cast<float4*>(&dv[q * 4]) = *reinterpret_cast<const float4*>(zd + q * 4);
        }
        #pragma unroll
        for (int e = 0; e < 2; ++e) {
            const int q  = (w & 1) * 2 + e;
            const int bs = (((w >> 1)) * 4 + l4) * 512 + (l15 + 16 * q) * 8;      // s: ks = w>>1
            const int bd = ((4 + (w >> 1)) * 4 + l4) * 512 + (l15 + 16 * q) * 8;  // d: ks = 4+(w>>1)
            SPLIT_STORE8(sv, e * 8, bs);
            SPLIT_STORE8(dv, e * 8, bd);
        }
    }

    // ---- prefetch epilogue-1 gather data (hidden under layer-1 MFMA) ----
    float ldS[4], ldD[4];
    #pragma unroll
    for (int nt = 0; nt < 4; ++nt) {
        const int pidx = (p0 + nt * 16 + l15 < N_PAIRS) ? (p0 + nt * 16 + l15) : (N_PAIRS - 1);
        ldS[nt] = logdeg[pairs[(size_t)pidx * 2 + 0]];
        ldD[nt] = logdeg[pairs[(size_t)pidx * 2 + 1]];
    }

    __syncthreads();

    // ---- layer 1: C^T = W1^T @ feat^T, K=512 in two 256-passes ----
    f32x4 acc[2][4];
    #pragma unroll
    for (int m = 0; m < 2; ++m)
        #pragma unroll
        for (int nt = 0; nt < 4; ++nt) acc[m][nt] = (f32x4){0.f, 0.f, 0.f, 0.f};

    auto run_pass = [&](int kbase) {
        bf16x8 wbh[2][2], wbl[2][2];
        #pragma unroll
        for (int m = 0; m < 2; ++m) {
            const size_t bo = ((size_t)((w * 2 + m) * 16 + kbase) * 64 + l) * 8;
            wbh[0][m] = *reinterpret_cast<const bf16x8*>(&w1h[bo]);
            wbl[0][m] = *reinterpret_cast<const bf16x8*>(&w1l[bo]);
        }
        #pragma unroll
        for (int ks = 0; ks < 8; ++ks) {
            const int cur = ks & 1;
            if (ks < 7) {
                #pragma unroll
                for (int m = 0; m < 2; ++m) {
                    const size_t bo = ((size_t)((w * 2 + m) * 16 + kbase + ks + 1) * 64 + l) * 8;
                    wbh[cur ^ 1][m] = *reinterpret_cast<const bf16x8*>(&w1h[bo]);
                    wbl[cur ^ 1][m] = *reinterpret_cast<const bf16x8*>(&w1l[bo]);
                }
            }
            bf16x8 fh[4], fl[4];
            #pragma unroll
            for (int nt = 0; nt < 4; ++nt) {
                const int fb = (ks * 4 + nt) * 512 + l * 8;
                fh[nt] = *reinterpret_cast<const bf16x8*>(&F[fb]);
                fl[nt] = *reinterpret_cast<const bf16x8*>(&F[16384 + fb]);
            }
            // product-major: 8 independent accumulators between dependent reuses
            #pragma unroll
            for (int m = 0; m < 2; ++m)
                #pragma unroll
                for (int nt = 0; nt < 4; ++nt)
                    acc[m][nt] = __builtin_amdgcn_mfma_f32_16x16x32_bf16(wbh[cur][m], fh[nt], acc[m][nt], 0, 0, 0);
            #pragma unroll
            for (int m = 0; m < 2; ++m)
                #pragma unroll
                for (int nt = 0; nt < 4; ++nt)
                    acc[m][nt] = __builtin_amdgcn_mfma_f32_16x16x32_bf16(wbl[cur][m], fh[nt], acc[m][nt], 0, 0, 0);
            #pragma unroll
            for (int m = 0; m < 2; ++m)
                #pragma unroll
                for (int nt = 0; nt < 4; ++nt)
                    acc[m][nt] = __builtin_amdgcn_mfma_f32_16x16x32_bf16(wbh[cur][m], fl[nt], acc[m][nt], 0, 0, 0);
        }
    };

    run_pass(0);

    // ---- transition: rebuild p = s*d, ad = |s-d| from own quantized s,d ----
    {
        float pv[16], av[16];
        #pragma unroll
        for (int e = 0; e < 2; ++e) {
            const int q  = (w & 1) * 2 + e;
            const int bs = (((w >> 1)) * 4 + l4) * 512 + (l15 + 16 * q) * 8;
            const int bd = ((4 + (w >> 1)) * 4 + l4) * 512 + (l15 + 16 * q) * 8;
            u32x4 sh = *reinterpret_cast<const u32x4*>(&F[bs]);
            u32x4 sl = *reinterpret_cast<const u32x4*>(&F[16384 + bs]);
            u32x4 dh = *reinterpret_cast<const u32x4*>(&F[bd]);
            u32x4 dl = *reinterpret_cast<const u32x4*>(&F[16384 + bd]);
            #pragma unroll
            for (int qq = 0; qq < 4; ++qq) {
                const float s0 = lo16f(sh[qq]) + lo16f(sl[qq]);
                const float s1 = hi16f(sh[qq]) + hi16f(sl[qq]);
                const float d0 = lo16f(dh[qq]) + lo16f(dl[qq]);
                const float d1 = hi16f(dh[qq]) + hi16f(dl[qq]);
                pv[e * 8 + 2 * qq]     = s0 * d0;
                pv[e * 8 + 2 * qq + 1] = s1 * d1;
                av[e * 8 + 2 * qq]     = fabsf(s0 - d0);
                av[e * 8 + 2 * qq + 1] = fabsf(s1 - d1);
            }
        }
        __syncthreads();   // all waves done reading pass-A frags
        #pragma unroll
        for (int e = 0; e < 2; ++e) {
            const int q  = (w & 1) * 2 + e;
            const int bp = (((w >> 1)) * 4 + l4) * 512 + (l15 + 16 * q) * 8;      // p -> slots 0..3
            const int ba = ((4 + (w >> 1)) * 4 + l4) * 512 + (l15 + 16 * q) * 8;  // ad -> slots 4..7
            SPLIT_STORE8(pv, e * 8, bp);
            SPLIT_STORE8(av, e * 8, ba);
        }
    }
    __syncthreads();

    run_pass(8);
    __syncthreads();   // all waves done reading pass-B frags

    // ---- epilogue 1: bias + logdeg rank-2 + relu; s1 frags overwrite F ----
    #pragma unroll
    for (int m = 0; m < 2; ++m) {
        const int mt = w * 2 + m;
        const int nb = mt * 16 + l4 * 4;
        float sb[4], wa[4], wb[4];
        *reinterpret_cast<float4*>(sb) = *reinterpret_cast<const float4*>(&Sb1[nb]);
        *reinterpret_cast<float4*>(wa) = *reinterpret_cast<const float4*>(&SW1[(size_t)512 * HID + nb]);
        *reinterpret_cast<float4*>(wb) = *reinterpret_cast<const float4*>(&SW1[(size_t)513 * HID + nb]);
        #pragma unroll
        for (int nt = 0; nt < 4; ++nt) {
            float v[4];
            #pragma unroll
            for (int r = 0; r < 4; ++r) {
                float x0 = acc[m][nt][r] + sb[r];
                x0 = fmaf(ldS[nt], wa[r], x0);
                x0 = fmaf(ldD[nt], wb[r], x0);
                v[r] = fmaxf(x0, 0.0f);
            }
            const unsigned h0 = pk2(v[0], v[1]);
            const unsigned h1 = pk2(v[2], v[3]);
            u32x2 hv, lv;
            hv[0] = h0; hv[1] = h1;
            lv[0] = pk2(v[0] - lo16f(h0), v[1] - hi16f(h0));
            lv[1] = pk2(v[2] - lo16f(h1), v[3] - hi16f(h1));
            const int base = (nt * 8 + (mt >> 1)) * 512
                           + (l15 + 16 * ((mt & 1) * 2 + (l4 >> 1))) * 8
                           + (l4 & 1) * 4;
            *reinterpret_cast<u32x2*>(&F[base])         = hv;
            *reinterpret_cast<u32x2*>(&F[16384 + base]) = lv;
        }
    }
    __syncthreads();

    // ---- layer 2: K=256, s1 frags from LDS, W2 frags (mt2 = w) from L2 ----
    f32x4 acc2[4];
    #pragma unroll
    for (int nt = 0; nt < 4; ++nt) acc2[nt] = (f32x4){0.f, 0.f, 0.f, 0.f};

    {
        bf16x8 wbh2[2], wbl2[2];
        {
            const size_t bo = ((size_t)(w * 8) * 64 + l) * 8;
            wbh2[0] = *reinterpret_cast<const bf16x8*>(&w2h[bo]);
            wbl2[0] = *reinterpret_cast<const bf16x8*>(&w2l[bo]);
        }
        #pragma unroll
        for (int ks = 0; ks < 8; ++ks) {
            const int cur = ks & 1;
            if (ks < 7) {
                const size_t bo = ((size_t)(w * 8 + ks + 1) * 64 + l) * 8;
                wbh2[cur ^ 1] = *reinterpret_cast<const bf16x8*>(&w2h[bo]);
                wbl2[cur ^ 1] = *reinterpret_cast<const bf16x8*>(&w2l[bo]);
            }
            bf16x8 fh[4], fl[4];
            #pragma unroll
            for (int nt = 0; nt < 4; ++nt) {
                const int fb = (nt * 8 + ks) * 512 + l * 8;
                fh[nt] = *reinterpret_cast<const bf16x8*>(&F[fb]);
                fl[nt] = *reinterpret_cast<const bf16x8*>(&F[16384 + fb]);
            }
            #pragma unroll
            for (int nt = 0; nt < 4; ++nt)
                acc2[nt] = __builtin_amdgcn_mfma_f32_16x16x32_bf16(wbh2[cur], fh[nt], acc2[nt], 0, 0, 0);
            #pragma unroll
            for (int nt = 0; nt < 4; ++nt)
                acc2[nt] = __builtin_amdgcn_mfma_f32_16x16x32_bf16(wbl2[cur], fh[nt], acc2[nt], 0, 0, 0);
            #pragma unroll
            for (int nt = 0; nt < 4; ++nt)
                acc2[nt] = __builtin_amdgcn_mfma_f32_16x16x32_bf16(wbh2[cur], fl[nt], acc2[nt], 0, 0, 0);
        }
    }

    // ---- epilogue 2 + layer 3: register dot with SW3, cross-lane+wave reduce ----
    {
        float part[4] = {0.f, 0.f, 0.f, 0.f};
        const int nb2 = w * 16 + l4 * 4;
        float sb[4], w3[4];
        *reinterpret_cast<float4*>(sb) = *reinterpret_cast<const float4*>(&Sb2[nb2]);
        *reinterpret_cast<float4*>(w3) = *reinterpret_cast<const float4*>(&SW3[nb2]);
        #pragma unroll
        for (int nt = 0; nt < 4; ++nt)
            #pragma unroll
            for (int r = 0; r < 4; ++r)
                part[nt] = fmaf(fmaxf(acc2[nt][r] + sb[r], 0.0f), w3[r], part[nt]);
        #pragma unroll
        for (int nt = 0; nt < 4; ++nt) {
            part[nt] += __shfl_xor(part[nt], 16);
            part[nt] += __shfl_xor(part[nt], 32);
        }
        if (l < 16) {
            #pragma unroll
            for (int nt = 0; nt < 4; ++nt) red[w][nt][l15] = part[nt];
        }
    }
    __syncthreads();

    if (t < 64) {
        const int nt = t >> 4, pp = t & 15;
        float v = Sb3[0];
        #pragma unroll
        for (int ww = 0; ww < 8; ++ww) v += red[ww][nt][pp];
        if (isnan(v)) v = 0.0f;
        else if (isinf(v)) v = (v > 0.0f) ? 20.0f : -20.0f;
        const int pidx = p0 + nt * 16 + pp;
        if (pidx < N_PAIRS) out[pidx] = v;
    }
    #undef SPLIT_STORE8
}

// ---------------------------------------------------------------------------
extern "C" void kernel_launch(void* const* d_in, const int* in_sizes, int n_in,
                              void* d_out, int out_size, void* d_ws, size_t ws_size,
                              hipStream_t stream)
{
    const float* x        = (const float*)d_in[0];
    // d_in[1] = edge_index : unused by the reference
    const int*   pairs    = (const int*)d_in[2];
    const float* x_mean   = (const float*)d_in[3];
    const float* x_std    = (const float*)d_in[4];
    const float* logdeg   = (const float*)d_in[5];
    const float* W1       = (const float*)d_in[6];
    const float* b1       = (const float*)d_in[7];
    const float* bn_gamma = (const float*)d_in[8];
    const float* bn_beta  = (const float*)d_in[9];
    const float* bn_mean  = (const float*)d_in[10];
    const float* bn_var   = (const float*)d_in[11];
    const float* W2       = (const float*)d_in[12];
    const float* b2       = (const float*)d_in[13];
    const float* SW1      = (const float*)d_in[14];
    const float* Sb1      = (const float*)d_in[15];
    const float* SW2      = (const float*)d_in[16];
    const float* Sb2      = (const float*)d_in[17];
    const float* SW3      = (const float*)d_in[18];
    const float* Sb3      = (const float*)d_in[19];

    float* outp = (float*)d_out;

    // ws layout
    char* wsb = (char*)d_ws;
    float* zbuf = (float*)wsb;                          // 51,200,000 B
    u16* w1h = (u16*)(wsb + 51200000);                  // 262144 B
    u16* w1l = (u16*)(wsb + 51462144);                  // 262144 B
    u16* w2h = (u16*)(wsb + 51724288);                  // 65536 B
    u16* w2l = (u16*)(wsb + 51789824);                  // 65536 B

    prep_weights<<<640, 256, 0, stream>>>(SW1, SW2, w1h, w1l, w2h, w2l);

    node_mlp_kernel<<<N_NODES / TA, 256, 0, stream>>>(
        x, x_mean, x_std, W1, b1, bn_gamma, bn_beta, bn_mean, bn_var, W2, b2, zbuf);

    pair_mfma_kernel<<<(N_PAIRS + PBM - 1) / PBM, 512, 0, stream>>>(
        zbuf, pairs, logdeg, w1h, w1l, w2h, w2l, SW1, Sb1, Sb2, SW3, Sb3, outp);
}

// Round 8
// 630.492 us; speedup vs baseline: 1.1914x; 1.1914x over previous
//
#include <hip/hip_runtime.h>
#include <hip/hip_bf16.h>
#include <math.h>

typedef unsigned short u16;
typedef __attribute__((ext_vector_type(8))) short bf16x8;
typedef __attribute__((ext_vector_type(4))) float f32x4;
typedef __attribute__((ext_vector_type(4))) unsigned u32x4;
typedef __attribute__((ext_vector_type(2))) unsigned u32x2;

#define N_NODES 100000
#define IN_CH 128
#define HID 256
#define EMB 128
#define N_PAIRS 500000
#define BN_EPS 1e-5f

#define TA 32   // nodes per block (kernel A)
#define PBM 64  // pairs per block (kernel B)

// ---- bf16 helpers ----
__device__ __forceinline__ u16 f2bf(float f) {            // scalar RNE (prep kernel)
    unsigned u = __builtin_bit_cast(unsigned, f);
    unsigned r = u + 0x7FFFu + ((u >> 16) & 1u);
    return (u16)(r >> 16);
}
__device__ __forceinline__ float bf2f(u16 h) {
    unsigned u = ((unsigned)h) << 16;
    return __builtin_bit_cast(float, u);
}
// packed pair conversion -> v_cvt_pk_bf16_f32
__device__ __forceinline__ unsigned pk2(float a, float b) {
    __hip_bfloat162 h = __float22bfloat162_rn(make_float2(a, b));
    unsigned u;
    __builtin_memcpy(&u, &h, sizeof(u));
    return u;
}
__device__ __forceinline__ float lo16f(unsigned u) { return __builtin_bit_cast(float, u << 16); }
__device__ __forceinline__ float hi16f(unsigned u) { return __builtin_bit_cast(float, u & 0xffff0000u); }

// ---------------------------------------------------------------------------
// Weight prep into MFMA A-operand fragment-linear layout (weights on M-side):
// idx = ((mt*KS + ks)*64 + l)*8 + j ; value = W[k][n], n = mt*16 + (l&15),
// k = ks*32 + (l>>4)*8 + j.
// ---------------------------------------------------------------------------
__global__ __launch_bounds__(256) void prep_weights(
    const float* __restrict__ SW1, const float* __restrict__ SW2,
    u16* __restrict__ w1h, u16* __restrict__ w1l,
    u16* __restrict__ w2h, u16* __restrict__ w2l)
{
    const int tid = blockIdx.x * 256 + threadIdx.x;
    if (tid < 131072) {                       // W1^T frags: 16 mt x 16 ks
        const int j = tid & 7, l = (tid >> 3) & 63, ks = (tid >> 9) & 15, mt = tid >> 13;
        const int n = mt * 16 + (l & 15);
        const int k = ks * 32 + ((l >> 4) << 3) + j;
        const float v = SW1[(size_t)k * HID + n];
        const u16 h = f2bf(v);
        w1h[tid] = h;
        w1l[tid] = f2bf(v - bf2f(h));
    } else if (tid < 131072 + 32768) {        // W2^T frags: 8 mt x 8 ks
        const int t2 = tid - 131072;
        const int j = t2 & 7, l = (t2 >> 3) & 63, ks = (t2 >> 9) & 7, mt = t2 >> 12;
        const int n = mt * 16 + (l & 15);
        const int k = ks * 32 + ((l >> 4) << 3) + j;
        const float v = SW2[(size_t)k * (HID / 2) + n];
        const u16 h = f2bf(v);
        w2h[t2] = h;
        w2l[t2] = f2bf(v - bf2f(h));
    }
}

// ---------------------------------------------------------------------------
// Kernel A: z = relu( relu(BN(clip((x-mean)/std) @ W1 + b1)) @ W2 + b2 )
// (unchanged — fp32 register-tiled)
// ---------------------------------------------------------------------------
__global__ __launch_bounds__(256) void node_mlp_kernel(
    const float* __restrict__ x,
    const float* __restrict__ x_mean,
    const float* __restrict__ x_std,
    const float* __restrict__ W1,
    const float* __restrict__ b1,
    const float* __restrict__ bn_gamma,
    const float* __restrict__ bn_beta,
    const float* __restrict__ bn_mean,
    const float* __restrict__ bn_var,
    const float* __restrict__ W2,
    const float* __restrict__ b2,
    float* __restrict__ z)
{
    __shared__ __align__(16) float xfT[IN_CH][36];
    __shared__ __align__(16) float hT[HID][36];

    const int t  = threadIdx.x;
    const int n0 = blockIdx.x * TA;

    for (int f = t; f < TA * (IN_CH / 4); f += 256) {
        const int n  = f >> 5;
        const int cg = f & 31;
        float4 v = *reinterpret_cast<const float4*>(x + (size_t)(n0 + n) * IN_CH + cg * 4);
        float vv[4] = {v.x, v.y, v.z, v.w};
        #pragma unroll
        for (int e = 0; e < 4; ++e) {
            const int c = cg * 4 + e;
            float val = vv[e];
            if (!isfinite(val)) val = 0.0f;
            val = (val - x_mean[c]) / x_std[c];
            val = fminf(fmaxf(val, -10.0f), 10.0f);
            xfT[c][n] = val;
        }
    }
    __syncthreads();

    const int i0 = t >> 6;
    const int j  = t & 63;

    {
        float acc[8][4];
        #pragma unroll
        for (int r = 0; r < 8; ++r)
            #pragma unroll
            for (int c = 0; c < 4; ++c) acc[r][c] = 0.0f;

        #pragma unroll 4
        for (int k = 0; k < IN_CH; ++k) {
            float a[8];
            *reinterpret_cast<float4*>(&a[0]) = *reinterpret_cast<const float4*>(&xfT[k][i0 * 8]);
            *reinterpret_cast<float4*>(&a[4]) = *reinterpret_cast<const float4*>(&xfT[k][i0 * 8 + 4]);
            float w[4];
            *reinterpret_cast<float4*>(w) = *reinterpret_cast<const float4*>(W1 + (size_t)k * HID + j * 4);
            #pragma unroll
            for (int r = 0; r < 8; ++r)
                #pragma unroll
                for (int c = 0; c < 4; ++c)
                    acc[r][c] = fmaf(a[r], w[c], acc[r][c]);
        }

        float b1v[4], gv[4], bev[4], mv[4], vv[4];
        *reinterpret_cast<float4*>(b1v) = *reinterpret_cast<const float4*>(b1 + j * 4);
        *reinterpret_cast<float4*>(gv)  = *reinterpret_cast<const float4*>(bn_gamma + j * 4);
        *reinterpret_cast<float4*>(bev) = *reinterpret_cast<const float4*>(bn_beta + j * 4);
        *reinterpret_cast<float4*>(mv)  = *reinterpret_cast<const float4*>(bn_mean + j * 4);
        *reinterpret_cast<float4*>(vv)  = *reinterpret_cast<const float4*>(bn_var + j * 4);

        #pragma unroll
        for (int c = 0; c < 4; ++c) {
            const float scale = gv[c] * rsqrtf(vv[c] + BN_EPS);
            float tmp[8];
            #pragma unroll
            for (int r = 0; r < 8; ++r) {
                const float hv = (acc[r][c] + b1v[c] - mv[c]) * scale + bev[c];
                tmp[r] = fmaxf(hv, 0.0f);
            }
            *reinterpret_cast<float4*>(&hT[j * 4 + c][i0 * 8])     = *reinterpret_cast<float4*>(&tmp[0]);
            *reinterpret_cast<float4*>(&hT[j * 4 + c][i0 * 8 + 4]) = *reinterpret_cast<float4*>(&tmp[4]);
        }
    }
    __syncthreads();

    {
        float acc[8][2];
        #pragma unroll
        for (int r = 0; r < 8; ++r) { acc[r][0] = 0.0f; acc[r][1] = 0.0f; }

        #pragma unroll 4
        for (int k = 0; k < HID; ++k) {
            float a[8];
            *reinterpret_cast<float4*>(&a[0]) = *reinterpret_cast<const float4*>(&hT[k][i0 * 8]);
            *reinterpret_cast<float4*>(&a[4]) = *reinterpret_cast<const float4*>(&hT[k][i0 * 8 + 4]);
            const float2 w = *reinterpret_cast<const float2*>(W2 + (size_t)k * EMB + j * 2);
            #pragma unroll
            for (int r = 0; r < 8; ++r) {
                acc[r][0] = fmaf(a[r], w.x, acc[r][0]);
                acc[r][1] = fmaf(a[r], w.y, acc[r][1]);
            }
        }
        const float2 b2v = *reinterpret_cast<const float2*>(b2 + j * 2);
        #pragma unroll
        for (int r = 0; r < 8; ++r) {
            float2 o;
            o.x = fmaxf(acc[r][0] + b2v.x, 0.0f);
            o.y = fmaxf(acc[r][1] + b2v.y, 0.0f);
            *reinterpret_cast<float2*>(z + (size_t)(n0 + i0 * 8 + r) * EMB + j * 2) = o;
        }
    }
}

// ---------------------------------------------------------------------------
// Kernel B (MFMA): 64 pairs/block, 4 waves (256 thr), ~33 KB LDS -> 4 blocks/CU.
// Layer 1: K=512 in FOUR 128-K segments through one 32 KB buffer:
//   seg0 = [s|d] ch 0:64   (weight ks {0,1,4,5})
//   seg2 = [p|ad] ch 0:64  (ks {8,9,12,13})   p,ad rebuilt from seg0's s~,d~
//   seg1 = [s|d] ch 64:128 (ks {2,3,6,7})     second-half z gather
//   seg3 = [p|ad] ch 64:128(ks {10,11,14,15})
// Layer 2: K=256 in 2 rounds; each wave stages its 32-col s1 slice into its
// own 8KB chunk slot (cs = w), reusing the same 32 KB buffer.
// Feature frag: F[(slot*4+nt)*512 + l*8 + j] = feat[pair nt*16+(l&15)][k=slot*32+(l>>4)*8+j]
// NOTE: no 2nd __launch_bounds__ arg — (512,4) forced 64-VGPR spill (r6),
// (512,2) forced 1-block residency (r7).
// ---------------------------------------------------------------------------
__global__ __launch_bounds__(256) void pair_mfma_kernel(
    const float* __restrict__ z,
    const int* __restrict__ pairs,
    const float* __restrict__ logdeg,
    const u16* __restrict__ w1h, const u16* __restrict__ w1l,
    const u16* __restrict__ w2h, const u16* __restrict__ w2l,
    const float* __restrict__ SW1, const float* __restrict__ Sb1,
    const float* __restrict__ Sb2,
    const float* __restrict__ SW3, const float* __restrict__ Sb3,
    float* __restrict__ out)
{
    __shared__ __align__(16) u16 F[2 * 8192];    // 32 KB: [half][slot 0..3][nt 0..3][512]
    __shared__ float red[4][4][16];              // 1 KB

    const int t   = threadIdx.x;
    const int w   = t >> 6;        // wave 0..3
    const int l   = t & 63;
    const int l15 = l & 15;
    const int l4  = l >> 4;
    const int p0  = blockIdx.x * PBM;

    // split 8 floats (vals[off..off+8)) and store hi/lo u32x4 at u16-index base
    #define SPLIT_STORE8(vals, off, base) { \
        u32x4 hv, lv; \
        _Pragma("unroll") \
        for (int q = 0; q < 4; ++q) { \
            const float a = (vals)[(off) + 2 * q]; \
            const float b = (vals)[(off) + 2 * q + 1]; \
            const unsigned hw = pk2(a, b); \
            hv[q] = hw; \
            lv[q] = pk2(a - lo16f(hw), b - hi16f(hw)); \
        } \
        *reinterpret_cast<u32x4*>(&F[(base)])        = hv; \
        *reinterpret_cast<u32x4*>(&F[8192 + (base)]) = lv; }

    // stage bases: thread (w,l) owns pair l, 16 channels [w*16, w*16+16) of a
    // 64-ch half; within segment, s-type -> slot (w>>1), d-type -> slot 2+(w>>1)
    #define BS(e) (((w >> 1) * 4 + l4) * 512 + (l15 + 16 * ((w & 1) * 2 + (e))) * 8)
    #define BD(e) (((2 + (w >> 1)) * 4 + l4) * 512 + (l15 + 16 * ((w & 1) * 2 + (e))) * 8)

    // ---- phase 0: gather s,d ch[0:64); stage seg0 ----
    const int gp  = (p0 + l < N_PAIRS) ? (p0 + l) : (N_PAIRS - 1);
    const int gsi = pairs[(size_t)gp * 2 + 0];
    const int gdi = pairs[(size_t)gp * 2 + 1];
    {
        const float* zs = z + (size_t)gsi * EMB + w * 16;
        const float* zd = z + (size_t)gdi * EMB + w * 16;
        float sv[16], dv[16];
        #pragma unroll
        for (int q = 0; q < 4; ++q) {
            *reinterpret_cast<float4*>(&sv[q * 4]) = *reinterpret_cast<const float4*>(zs + q * 4);
            *reinterpret_cast<float4*>(&dv[q * 4]) = *reinterpret_cast<const float4*>(zd + q * 4);
        }
        #pragma unroll
        for (int e = 0; e < 2; ++e) {
            SPLIT_STORE8(sv, e * 8, BS(e));
            SPLIT_STORE8(dv, e * 8, BD(e));
        }
    }

    // ---- prefetch epilogue-1 gather data (hidden under layer-1 MFMA) ----
    float ldS[4], ldD[4];
    #pragma unroll
    for (int nt = 0; nt < 4; ++nt) {
        const int pidx = (p0 + nt * 16 + l15 < N_PAIRS) ? (p0 + nt * 16 + l15) : (N_PAIRS - 1);
        ldS[nt] = logdeg[pairs[(size_t)pidx * 2 + 0]];
        ldD[nt] = logdeg[pairs[(size_t)pidx * 2 + 1]];
    }

    __syncthreads();

    // ---- layer 1 accumulators ----
    f32x4 acc[4][4];
    #pragma unroll
    for (int m = 0; m < 4; ++m)
        #pragma unroll
        for (int nt = 0; nt < 4; ++nt) acc[m][nt] = (f32x4){0.f, 0.f, 0.f, 0.f};

    // one 128-K segment: slots 0..3 map to weight ks {k0,k1,k2,k3}
    auto run_pass = [&](int k0, int k1, int k2, int k3) {
        const int ksg[4] = {k0, k1, k2, k3};
        #pragma unroll
        for (int sl = 0; sl < 4; ++sl) {
            bf16x8 wh[4], wl[4];
            #pragma unroll
            for (int m = 0; m < 4; ++m) {
                const size_t bo = ((size_t)((w * 4 + m) * 16 + ksg[sl]) * 64 + l) * 8;
                wh[m] = *reinterpret_cast<const bf16x8*>(&w1h[bo]);
                wl[m] = *reinterpret_cast<const bf16x8*>(&w1l[bo]);
            }
            bf16x8 fh[4], fl[4];
            #pragma unroll
            for (int nt = 0; nt < 4; ++nt) {
                const int fb = (sl * 4 + nt) * 512 + l * 8;
                fh[nt] = *reinterpret_cast<const bf16x8*>(&F[fb]);
                fl[nt] = *reinterpret_cast<const bf16x8*>(&F[8192 + fb]);
            }
            #pragma unroll
            for (int m = 0; m < 4; ++m)
                #pragma unroll
                for (int nt = 0; nt < 4; ++nt)
                    acc[m][nt] = __builtin_amdgcn_mfma_f32_16x16x32_bf16(wh[m], fh[nt], acc[m][nt], 0, 0, 0);
            #pragma unroll
            for (int m = 0; m < 4; ++m)
                #pragma unroll
                for (int nt = 0; nt < 4; ++nt)
                    acc[m][nt] = __builtin_amdgcn_mfma_f32_16x16x32_bf16(wl[m], fh[nt], acc[m][nt], 0, 0, 0);
            #pragma unroll
            for (int m = 0; m < 4; ++m)
                #pragma unroll
                for (int nt = 0; nt < 4; ++nt)
                    acc[m][nt] = __builtin_amdgcn_mfma_f32_16x16x32_bf16(wh[m], fl[nt], acc[m][nt], 0, 0, 0);
        }
    };

    // transition: read own quantized s~,d~ back from current [s|d] segment,
    // compute p = s~*d~, ad = |s~-d~| (16 each)
    auto rebuild = [&](float* pv, float* av) {
        #pragma unroll
        for (int e = 0; e < 2; ++e) {
            const int bs = BS(e);
            const int bd = BD(e);
            u32x4 sh = *reinterpret_cast<const u32x4*>(&F[bs]);
            u32x4 sl = *reinterpret_cast<const u32x4*>(&F[8192 + bs]);
            u32x4 dh = *reinterpret_cast<const u32x4*>(&F[bd]);
            u32x4 dl = *reinterpret_cast<const u32x4*>(&F[8192 + bd]);
            #pragma unroll
            for (int qq = 0; qq < 4; ++qq) {
                const float s0 = lo16f(sh[qq]) + lo16f(sl[qq]);
                const float s1 = hi16f(sh[qq]) + hi16f(sl[qq]);
                const float d0 = lo16f(dh[qq]) + lo16f(dl[qq]);
                const float d1 = hi16f(dh[qq]) + hi16f(dl[qq]);
                pv[e * 8 + 2 * qq]     = s0 * d0;
                pv[e * 8 + 2 * qq + 1] = s1 * d1;
                av[e * 8 + 2 * qq]     = fabsf(s0 - d0);
                av[e * 8 + 2 * qq + 1] = fabsf(s1 - d1);
            }
        }
    };

    // ---- seg0: [s|d] ch 0:64 ----
    run_pass(0, 1, 4, 5);
    {
        float pv[16], av[16];
        rebuild(pv, av);              // reads seg0 (still valid)
        __syncthreads();              // everyone done reading seg0
        #pragma unroll
        for (int e = 0; e < 2; ++e) { SPLIT_STORE8(pv, e * 8, BS(e)); SPLIT_STORE8(av, e * 8, BD(e)); }
    }
    __syncthreads();

    // ---- seg2: [p|ad] ch 0:64 ----
    run_pass(8, 9, 12, 13);
    __syncthreads();                  // done reading seg2 before overwrite

    // ---- seg1: [s|d] ch 64:128 (second-half z gather) ----
    {
        const float* zs = z + (size_t)gsi * EMB + 64 + w * 16;
        const float* zd = z + (size_t)gdi * EMB + 64 + w * 16;
        float sv[16], dv[16];
        #pragma unroll
        for (int q = 0; q < 4; ++q) {
            *reinterpret_cast<float4*>(&sv[q * 4]) = *reinterpret_cast<const float4*>(zs + q * 4);
            *reinterpret_cast<float4*>(&dv[q * 4]) = *reinterpret_cast<const float4*>(zd + q * 4);
        }
        #pragma unroll
        for (int e = 0; e < 2; ++e) {
            SPLIT_STORE8(sv, e * 8, BS(e));
            SPLIT_STORE8(dv, e * 8, BD(e));
        }
    }
    __syncthreads();

    run_pass(2, 3, 6, 7);
    {
        float pv[16], av[16];
        rebuild(pv, av);              // reads seg1
        __syncthreads();
        #pragma unroll
        for (int e = 0; e < 2; ++e) { SPLIT_STORE8(pv, e * 8, BS(e)); SPLIT_STORE8(av, e * 8, BD(e)); }
    }
    __syncthreads();

    // ---- seg3: [p|ad] ch 64:128 ----
    run_pass(10, 11, 14, 15);
    __syncthreads();                  // layer 1 done; F reusable

    // ---- layer 2: 2 rounds; round g stages m in {2g,2g+1} (chunk c = 2w+g) ----
    f32x4 acc2[2][4];
    #pragma unroll
    for (int m2 = 0; m2 < 2; ++m2)
        #pragma unroll
        for (int nt = 0; nt < 4; ++nt) acc2[m2][nt] = (f32x4){0.f, 0.f, 0.f, 0.f};

    #pragma unroll
    for (int g = 0; g < 2; ++g) {
        // epilogue-1 + stage: s1 values for m = 2g, 2g+1 -> chunk slot cs = w
        #pragma unroll
        for (int mm = 0; mm < 2; ++mm) {
            const int m  = 2 * g + mm;
            const int mt = w * 4 + m;
            const int nb = mt * 16 + l4 * 4;
            float sb[4], wa[4], wb[4];
            *reinterpret_cast<float4*>(sb) = *reinterpret_cast<const float4*>(&Sb1[nb]);
            *reinterpret_cast<float4*>(wa) = *reinterpret_cast<const float4*>(&SW1[(size_t)512 * HID + nb]);
            *reinterpret_cast<float4*>(wb) = *reinterpret_cast<const float4*>(&SW1[(size_t)513 * HID + nb]);
            #pragma unroll
            for (int nt = 0; nt < 4; ++nt) {
                float v[4];
                #pragma unroll
                for (int r = 0; r < 4; ++r) {
                    float x0 = acc[m][nt][r] + sb[r];
                    x0 = fmaf(ldS[nt], wa[r], x0);
                    x0 = fmaf(ldD[nt], wb[r], x0);
                    v[r] = fmaxf(x0, 0.0f);
                }
                const unsigned h0 = pk2(v[0], v[1]);
                const unsigned h1 = pk2(v[2], v[3]);
                u32x2 hv, lv;
                hv[0] = h0; hv[1] = h1;
                lv[0] = pk2(v[0] - lo16f(h0), v[1] - hi16f(h0));
                lv[1] = pk2(v[2] - lo16f(h1), v[3] - hi16f(h1));
                const int base = (w * 4 + nt) * 512
                               + (l15 + 16 * ((m & 1) * 2 + (l4 >> 1))) * 8
                               + (l4 & 1) * 4;
                *reinterpret_cast<u32x2*>(&F[base])        = hv;
                *reinterpret_cast<u32x2*>(&F[8192 + base]) = lv;
            }
        }
        __syncthreads();

        // MFMA: 4 chunk slots, chunk c = cs*2 + g -> layer-2 ks2 = c
        #pragma unroll
        for (int cs = 0; cs < 4; ++cs) {
            const int ks2 = cs * 2 + g;
            bf16x8 wh2[2], wl2[2];
            #pragma unroll
            for (int m2 = 0; m2 < 2; ++m2) {
                const size_t bo = ((size_t)((w * 2 + m2) * 8 + ks2) * 64 + l) * 8;
                wh2[m2] = *reinterpret_cast<const bf16x8*>(&w2h[bo]);
                wl2[m2] = *reinterpret_cast<const bf16x8*>(&w2l[bo]);
            }
            bf16x8 fh[4], fl[4];
            #pragma unroll
            for (int nt = 0; nt < 4; ++nt) {
                const int fb = (cs * 4 + nt) * 512 + l * 8;
                fh[nt] = *reinterpret_cast<const bf16x8*>(&F[fb]);
                fl[nt] = *reinterpret_cast<const bf16x8*>(&F[8192 + fb]);
            }
            #pragma unroll
            for (int m2 = 0; m2 < 2; ++m2)
                #pragma unroll
                for (int nt = 0; nt < 4; ++nt)
                    acc2[m2][nt] = __builtin_amdgcn_mfma_f32_16x16x32_bf16(wh2[m2], fh[nt], acc2[m2][nt], 0, 0, 0);
            #pragma unroll
            for (int m2 = 0; m2 < 2; ++m2)
                #pragma unroll
                for (int nt = 0; nt < 4; ++nt)
                    acc2[m2][nt] = __builtin_amdgcn_mfma_f32_16x16x32_bf16(wl2[m2], fh[nt], acc2[m2][nt], 0, 0, 0);
            #pragma unroll
            for (int m2 = 0; m2 < 2; ++m2)
                #pragma unroll
                for (int nt = 0; nt < 4; ++nt)
                    acc2[m2][nt] = __builtin_amdgcn_mfma_f32_16x16x32_bf16(wh2[m2], fl[nt], acc2[m2][nt], 0, 0, 0);
        }
        __syncthreads();   // before round-1 staging overwrites
    }

    // ---- epilogue 2 + layer 3: register dot with SW3, cross-lane+wave reduce ----
    {
        float part[4] = {0.f, 0.f, 0.f, 0.f};
        #pragma unroll
        for (int m2 = 0; m2 < 2; ++m2) {
            const int nb2 = (w * 2 + m2) * 16 + l4 * 4;
            float sb[4], w3[4];
            *reinterpret_cast<float4*>(sb) = *reinterpret_cast<const float4*>(&Sb2[nb2]);
            *reinterpret_cast<float4*>(w3) = *reinterpret_cast<const float4*>(&SW3[nb2]);
            #pragma unroll
            for (int nt = 0; nt < 4; ++nt)
                #pragma unroll
                for (int r = 0; r < 4; ++r)
                    part[nt] = fmaf(fmaxf(acc2[m2][nt][r] + sb[r], 0.0f), w3[r], part[nt]);
        }
        #pragma unroll
        for (int nt = 0; nt < 4; ++nt) {
            part[nt] += __shfl_xor(part[nt], 16);
            part[nt] += __shfl_xor(part[nt], 32);
        }
        if (l < 16) {
            #pragma unroll
            for (int nt = 0; nt < 4; ++nt) red[w][nt][l15] = part[nt];
        }
    }
    __syncthreads();

    if (t < 64) {
        const int nt = t >> 4, pp = t & 15;
        float v = red[0][nt][pp] + red[1][nt][pp] + red[2][nt][pp] + red[3][nt][pp] + Sb3[0];
        if (isnan(v)) v = 0.0f;
        else if (isinf(v)) v = (v > 0.0f) ? 20.0f : -20.0f;
        const int pidx = p0 + nt * 16 + pp;
        if (pidx < N_PAIRS) out[pidx] = v;
    }
    #undef SPLIT_STORE8
    #undef BS
    #undef BD
}

// ---------------------------------------------------------------------------
extern "C" void kernel_launch(void* const* d_in, const int* in_sizes, int n_in,
                              void* d_out, int out_size, void* d_ws, size_t ws_size,
                              hipStream_t stream)
{
    const float* x        = (const float*)d_in[0];
    // d_in[1] = edge_index : unused by the reference
    const int*   pairs    = (const int*)d_in[2];
    const float* x_mean   = (const float*)d_in[3];
    const float* x_std    = (const float*)d_in[4];
    const float* logdeg   = (const float*)d_in[5];
    const float* W1       = (const float*)d_in[6];
    const float* b1       = (const float*)d_in[7];
    const float* bn_gamma = (const float*)d_in[8];
    const float* bn_beta  = (const float*)d_in[9];
    const float* bn_mean  = (const float*)d_in[10];
    const float* bn_var   = (const float*)d_in[11];
    const float* W2       = (const float*)d_in[12];
    const float* b2       = (const float*)d_in[13];
    const float* SW1      = (const float*)d_in[14];
    const float* Sb1      = (const float*)d_in[15];
    const float* SW2      = (const float*)d_in[16];
    const float* Sb2      = (const float*)d_in[17];
    const float* SW3      = (const float*)d_in[18];
    const float* Sb3      = (const float*)d_in[19];

    float* outp = (float*)d_out;

    // ws layout
    char* wsb = (char*)d_ws;
    float* zbuf = (float*)wsb;                          // 51,200,000 B
    u16* w1h = (u16*)(wsb + 51200000);                  // 262144 B
    u16* w1l = (u16*)(wsb + 51462144);                  // 262144 B
    u16* w2h = (u16*)(wsb + 51724288);                  // 65536 B
    u16* w2l = (u16*)(wsb + 51789824);                  // 65536 B

    prep_weights<<<640, 256, 0, stream>>>(SW1, SW2, w1h, w1l, w2h, w2l);

    node_mlp_kernel<<<N_NODES / TA, 256, 0, stream>>>(
        x, x_mean, x_std, W1, b1, bn_gamma, bn_beta, bn_mean, bn_var, W2, b2, zbuf);

    pair_mfma_kernel<<<(N_PAIRS + PBM - 1) / PBM, 256, 0, stream>>>(
        zbuf, pairs, logdeg, w1h, w1l, w2h, w2l, SW1, Sb1, Sb2, SW3, Sb3, outp);
}